// Round 4
// baseline (115.044 us; speedup 1.0000x reference)
//
#include <hip/hip_runtime.h>
#include <stdint.h>

// ConvMemory v5 (split): out = (3x3 conv of E=exp(x), W=memory) / (3x3 boxsum of chan-sum(E))
// exp_tr4: NCHW f32 -> per-pixel granules (g holds ch 8g..8g+7, pair-packed bf16)
//          + per-pixel rounded channel-sum S.  Pure streaming, latency-tolerant.
// convf:   slim MFMA kernel. Swizzled-SOURCE staging (lane fetches granule
//          g = slot ^ ((p>>1)&7) -> conflict-free linear b128 LDS writes, wave
//          reads a contiguous permuted 1KB), S loaded directly, ONE barrier,
//          verified 36x(2 MFMA) K-loop, Zinv inlined in epilogue.

#define Cn 64
#define Hn 128
#define Wn 128
#define OC 128
#define HW (Hn * Wn)

typedef __attribute__((ext_vector_type(8))) short bf16x8_t;
typedef __attribute__((ext_vector_type(16))) float f32x16_t;

__device__ inline unsigned short f2bf(float f) {
    union { float f; uint32_t u; } v; v.f = f;
    uint32_t u = v.u;
    u += 0x7fffu + ((u >> 16) & 1u);
    return (unsigned short)(u >> 16);
}
__device__ inline float bf_lo(uint32_t u) {
    union { uint32_t u; float f; } v; v.u = u << 16;
    return v.f;
}
__device__ inline float bf_hi(uint32_t u) {
    union { uint32_t u; float f; } v; v.u = u & 0xffff0000u;
    return v.f;
}

// ---------------------------------------------------------------------------
// prep: memory[576][128] f32 -> Bt2 bf16 chunks: chunk cid=(kc*2+hi), 128 n's,
// 16B per n = 8 channels c = (kc&3)*16 + hi*8 + j, q = kc>>2 (kh*3+kw).
// Block 36 writes the 128B "ones page" (bf16 1.0) used for OOB halo pixels.
// ---------------------------------------------------------------------------
__global__ void prep_b2(const float* __restrict__ mem, uint4* __restrict__ Bt2,
                        uint4* __restrict__ ones) {
    if (blockIdx.x == 36) {
        if (threadIdx.x < 8)
            ones[threadIdx.x] = make_uint4(0x3F803F80u, 0x3F803F80u, 0x3F803F80u, 0x3F803F80u);
        return;
    }
    int u = blockIdx.x * 256 + threadIdx.x;   // 0..9215
    int n = u & 127;
    int cid = u >> 7;                         // 0..71
    int hi = cid & 1;
    int kc = cid >> 1;                        // 0..35
    int q = kc >> 2, cblk = kc & 3;
    unsigned short h8[8];
#pragma unroll
    for (int j = 0; j < 8; j++) {
        int c = cblk * 16 + hi * 8 + j;
        h8[j] = f2bf(mem[(c * 9 + q) * OC + n]);
    }
    Bt2[cid * 128 + n] = *(const uint4*)h8;
}

// ---------------------------------------------------------------------------
// exp_tr4: per (b,h) row. Phase 1: wave wv handles channel pairs cp=wv*8+i;
// lane reads float2 from rows 2cp,2cp+1, exps, packs (c,c+1) per pixel into
// u32, ds_write_b64 conflict-free into L[cp][w]. Rounded-value partial sums.
// Phase 2: thread (w=t>>1, half=t&1) reads 16 b32, 4 uint4 stores, S reduce.
// Et global layout: pixel*128B, granule g (16B) = channels 8g..8g+7.
// ---------------------------------------------------------------------------
__global__ __launch_bounds__(256) void exp_tr4(const float* __restrict__ x,
                                               uint4* __restrict__ Etu,
                                               float* __restrict__ S) {
    __shared__ uint32_t L[32 * 132];     // [cp][w], pad 128->132 u32
    __shared__ float Spart[512];
    int bid = blockIdx.x;            // 1024 = 8 b * 128 h
    int b = bid >> 7, h = bid & 127;
    int t = threadIdx.x;
    int wv = t >> 6, lane = t & 63;

    const float* xr = x + (size_t)b * Cn * HW + h * Wn;
    float s0 = 0.f, s1 = 0.f;
#pragma unroll
    for (int i = 0; i < 8; i++) {
        int cp = wv * 8 + i;
        const float* r0 = xr + (size_t)(2 * cp) * HW + 2 * lane;
        float2 v0 = *(const float2*)r0;
        float2 v1 = *(const float2*)(r0 + HW);
        uint32_t p0 = (uint32_t)f2bf(__expf(v0.x)) | ((uint32_t)f2bf(__expf(v1.x)) << 16);
        uint32_t p1 = (uint32_t)f2bf(__expf(v0.y)) | ((uint32_t)f2bf(__expf(v1.y)) << 16);
        s0 += bf_lo(p0) + bf_hi(p0);
        s1 += bf_lo(p1) + bf_hi(p1);
        *(uint2*)&L[cp * 132 + 2 * lane] = make_uint2(p0, p1);
    }
    *(float2*)&Spart[wv * 128 + 2 * lane] = make_float2(s0, s1);
    __syncthreads();

    int w = t >> 1, half = t & 1;
    uint32_t us[16];
#pragma unroll
    for (int j = 0; j < 16; j++)
        us[j] = L[(half * 16 + j) * 132 + w];
    size_t pix = (size_t)(b * Hn + h) * Wn + w;
    uint4* dst = Etu + pix * 8 + half * 4;
    const uint4* sv = (const uint4*)us;
    dst[0] = sv[0]; dst[1] = sv[1]; dst[2] = sv[2]; dst[3] = sv[3];

    if (half == 0)
        S[pix] = Spart[w] + Spart[128 + w] + Spart[256 + w] + Spart[384 + w];
}

// ---------------------------------------------------------------------------
// convf: 512 threads = 8 waves, 8x16 tile, 1024 blocks (XCD-chunk swizzled).
// Wave = 64 px x 32 oc -> acc[2] f32x16. ONE barrier.
// ---------------------------------------------------------------------------
__global__ __launch_bounds__(512, 4) void convf(const uint4* __restrict__ Etu,
                                                const uint4* __restrict__ Bt2,
                                                const float* __restrict__ S,
                                                const uint4* __restrict__ ones,
                                                float* __restrict__ out) {
    __shared__ __align__(16) uint4 EtL[184 * 8];   // 23552 B, [p][slot], 10x18 halo (pad->184)
    __shared__ float Sh[184];

    int bid0 = blockIdx.x;
    int bid = ((bid0 & 7) << 7) | (bid0 >> 3);   // XCD chunk swizzle, 1024 = 8*128
    int b = bid >> 7;                            // 8 b * 16 ty * 8 tx
    int ty = (bid >> 3) & 15, tx = bid & 7;
    int h0 = ty * 8, w0 = tx * 16;
    int t = threadIdx.x;
    int lane = t & 63, wv = t >> 6;

    const uint4* Etb = Etu + (size_t)b * HW * 8;

    // ---- stage Et halo: 23 groups of 8 px; lane = (pr=l>>3, slot=l&7).
    // Source granule g = slot ^ ((p>>1)&7): wave reads contiguous permuted 1KB,
    // writes linear b128 (2-way, free). OOB lanes read the global ones page.
    {
        int pr = lane >> 3, slot = lane & 7;
#pragma unroll
        for (int i = 0; i < 3; i++) {
            int grp = wv + 8 * i;
            if (grp < 23) {
                int p = grp * 8 + pr;             // 0..183
                int py = p / 18, px = p - py * 18;
                int gy = h0 - 1 + py, gx = w0 - 1 + px;
                bool in = (p < 180) & (gy >= 0) & (gy < Hn) & (gx >= 0) & (gx < Wn);
                int g = slot ^ ((p >> 1) & 7);
                const uint4* src = in ? (Etb + ((size_t)(gy * Wn + gx)) * 8 + g)
                                      : (ones + g);
                EtL[p * 8 + slot] = *src;
            }
        }
    }
    // ---- stage S halo ----
    if (t < 184) {
        int py = t / 18, px = t - py * 18;
        int gy = h0 - 1 + py, gx = w0 - 1 + px;
        bool in = (t < 180) & (gy >= 0) & (gy < Hn) & (gx >= 0) & (gx < Wn);
        Sh[t] = in ? S[(size_t)b * HW + gy * Wn + gx] : 64.0f;
    }
    __syncthreads();

    // ---- MFMA K-loop: wave = 64 px x 32 oc; 36 chunks of K=16, 3-deep prefetch ----
    int wid = wv;                     // 0..7
    int wo = wid & 3;                 // oc 32-block
    int wp = wid >> 2;                // px-pair 0..1
    int l31 = lane & 31, hi = lane >> 5;
    int x0v = l31 & 15;
    int y0[2];
    y0[0] = (wp * 2 + 0) * 2 + (l31 >> 4);
    y0[1] = (wp * 2 + 1) * 2 + (l31 >> 4);

    f32x16_t acc[2];
#pragma unroll
    for (int j = 0; j < 2; j++)
#pragma unroll
        for (int r = 0; r < 16; r++) acc[j][r] = 0.f;

    bf16x8_t Wf[3], Ef[3][2];

    auto loadW = [&](int kc, int s) {
        Wf[s] = *(const bf16x8_t*)(Bt2 + (size_t)((kc * 2 + hi) * 128 + wo * 32 + l31));
    };
    auto loadE = [&](int kc, int s) {
        int q = kc >> 2, cblk = kc & 3;
        int kh = q / 3, kw = q - kh * 3;
        int ge = cblk * 2 + hi;
#pragma unroll
        for (int j = 0; j < 2; j++) {
            int pix = (y0[j] + kh) * 18 + (x0v + kw);
            Ef[s][j] = *(const bf16x8_t*)&EtL[pix * 8 + (ge ^ ((pix >> 1) & 7))];
        }
    };

    loadW(0, 0); loadE(0, 0);
    loadW(1, 1); loadE(1, 1);
    loadW(2, 2); loadE(2, 2);
#pragma unroll
    for (int kc = 0; kc < 36; kc++) {
        int s = kc % 3;
#pragma unroll
        for (int j = 0; j < 2; j++)
            acc[j] = __builtin_amdgcn_mfma_f32_32x32x16_bf16(
                Wf[s], Ef[s][j], acc[j], 0, 0, 0);
        if (kc + 3 < 36) { loadW(kc + 3, s); loadE(kc + 3, s); }
    }

    // ---- epilogue: inline Zinv (3x3 boxsum of Sh), then scaled stores ----
#pragma unroll
    for (int j = 0; j < 2; j++) {
        float z = 0.f;
#pragma unroll
        for (int dy = 0; dy < 3; dy++)
#pragma unroll
            for (int dx = 0; dx < 3; dx++)
                z += Sh[(y0[j] + dy) * 18 + (x0v + dx)];
        float zi = 1.0f / z;
        float* ob = out + (size_t)b * OC * HW + (size_t)(wo * 32 + 4 * hi) * HW
                  + (h0 + y0[j]) * Wn + (w0 + x0v);
#pragma unroll
        for (int r = 0; r < 16; r++) {
            int nrel = (r & 3) + 8 * (r >> 2);   // + 4*hi folded into ob
            ob[(size_t)nrel * HW] = acc[j][r] * zi;
        }
    }
}

// ---------------------------------------------------------------------------
extern "C" void kernel_launch(void* const* d_in, const int* in_sizes, int n_in,
                              void* d_out, int out_size, void* d_ws, size_t ws_size,
                              hipStream_t stream) {
    const float* x = (const float*)d_in[0];
    const float* mem = (const float*)d_in[1];
    float* out = (float*)d_out;
    char* ws = (char*)d_ws;

    uint4* Etu = (uint4*)ws;                               // 16,777,216 B
    float* S = (float*)(ws + 16777216);                    //    524,288 B
    uint4* Bt2 = (uint4*)(ws + 17301504);                  //    147,456 B
    uint4* ones = (uint4*)(ws + 17448960);                 //        128 B

    prep_b2<<<37, 256, 0, stream>>>(mem, Bt2, ones);
    exp_tr4<<<1024, 256, 0, stream>>>(x, Etu, S);
    convf<<<1024, 512, 0, stream>>>(Etu, Bt2, S, ones, out);
}